// Round 1
// baseline (653.813 us; speedup 1.0000x reference)
//
#include <hip/hip_runtime.h>

typedef __bf16 bf16x8 __attribute__((ext_vector_type(8)));
typedef float f32x4 __attribute__((ext_vector_type(4)));

#define LSEQ 8192
#define DDIM 64
#define QS 256
#define VOCAB 1027
#define RELK_ELEMS (VOCAB * DDIM)       // 65728
#define RELVT_PITCH 768
#define RELVT_ELEMS (DDIM * RELVT_PITCH) // 49152

__device__ __forceinline__ int swze(int row) { return ((row ^ (row >> 3)) & 7) << 3; }

__device__ __forceinline__ f32x4 mfma16(bf16x8 a, bf16x8 b, f32x4 c) {
  return __builtin_amdgcn_mfma_f32_16x16x32_bf16(a, b, c, 0, 0, 0);
}

__device__ __forceinline__ bf16x8 cvt8(float4 a, float4 b, float sc) {
  bf16x8 r;
  r[0] = (__bf16)(a.x * sc); r[1] = (__bf16)(a.y * sc);
  r[2] = (__bf16)(a.z * sc); r[3] = (__bf16)(a.w * sc);
  r[4] = (__bf16)(b.x * sc); r[5] = (__bf16)(b.y * sc);
  r[6] = (__bf16)(b.z * sc); r[7] = (__bf16)(b.w * sc);
  return r;
}

// Pre-convert rel tables to bf16: relk[t][d] row-major; relvT[d][j] = rel_v[j+2][d]
// (shift by 2 makes all fragment loads 16B-aligned since c0w = 194 - row_base == 2 mod 8).
__global__ void prep_kernel(const float* __restrict__ rk, const float* __restrict__ rv,
                            __bf16* __restrict__ relk, __bf16* __restrict__ relvT) {
  int i = blockIdx.x * 256 + threadIdx.x;
  if (i < RELK_ELEMS) relk[i] = (__bf16)rk[i];
  if (i < RELVT_ELEMS) {
    int d = i / RELVT_PITCH, j = i - d * RELVT_PITCH;
    relvT[i] = (__bf16)rv[(j + 2) * DDIM + d];
  }
}

// One WG = 64 q-rows of one 256-row block, 4 waves x 16 rows, window 512 in two 256-chunks.
__global__ __launch_bounds__(256, 2) void attn_kernel(
    const float* __restrict__ qg, const float* __restrict__ kg, const float* __restrict__ vg,
    const __bf16* __restrict__ relk, const __bf16* __restrict__ relvT,
    float* __restrict__ outg) {
  __shared__ __align__(16) __bf16 bufA[QS * DDIM];  // 32KB: K chunk [256][64] then vT [64][256]
  __shared__ __align__(16) __bf16 pbuf[64 * 256];   // 32KB: P (bf16) for current chunk
  __shared__ float ring[4][2][16][16];              // 8KB: per-wave QR tile ring

  // XCD-aware decode: 4 row-group siblings of one (bh,n) land on one XCD (round-robin assumption)
  const int phys = blockIdx.x;
  const int xcd = phys & 7;
  const int mseq = phys >> 3;
  const int rg = mseq & 3;
  const int gl = mseq >> 2;
  const int pair = xcd * 64 + gl;  // [0,512)
  const int bh = pair >> 5;
  const int nblk = pair & 31;
  const int x0 = rg * 64;

  const int tid = threadIdx.x;
  const int w = tid >> 6;
  const int lane = tid & 63;
  const int c16 = lane & 15;
  const int grp = lane >> 4;

  const int row_base = x0 + 16 * w;   // wave's first q row within the 256-block
  const int c0w = 194 - row_base;     // relk row offset: t = c0w + u
  const int j0w = 192 - row_base;     // relvT col offset (shifted table): j = j0w + u

  // q A-fragments (A[row=l&15][k=32*kk+8*grp+i]), pre-scaled by D^-0.5 = 1/8
  bf16x8 qa[2];
  {
    const float* qrow = qg + (size_t)(bh * LSEQ + nblk * QS + row_base + c16) * DDIM;
#pragma unroll
    for (int kk = 0; kk < 2; ++kk) {
      const float4* sp = (const float4*)(qrow + kk * 32 + grp * 8);
      qa[kk] = cvt8(sp[0], sp[1], 0.125f);
    }
  }

  f32x4 o[4];
#pragma unroll
  for (int jd = 0; jd < 4; ++jd) o[jd] = f32x4{0.f, 0.f, 0.f, 0.f};
  float mrun[4] = {-1e30f, -1e30f, -1e30f, -1e30f};
  float lsum[4] = {0.f, 0.f, 0.f, 0.f};

  const int cstart = (nblk == 0) ? 1 : 0;  // n=0: window cols [0,256) are all padding/masked

  for (int c = cstart; c < 2; ++c) {
    __syncthreads();
    // ---- stage K chunk: window y = 256c+yc  <->  global k row (nblk+c-1)*256 + yc ----
    {
      const int ty = tid >> 3, td = tid & 7;
      const int d0 = td * 8;
      const float* kb = kg + (size_t)(bh * LSEQ + (nblk + c - 1) * QS) * DDIM;
#pragma unroll
      for (int rep = 0; rep < 8; ++rep) {
        int yc = ty + rep * 32;
        const float4* sp = (const float4*)(kb + yc * DDIM + d0);
        bf16x8 val = cvt8(sp[0], sp[1], 1.0f);
        *(bf16x8*)&bufA[yc * 64 + (d0 ^ swze(yc))] = val;
      }
    }
    __syncthreads();

    // ---- S = q@k^T + skew(q@relk^T), masked ----
    float sv[16][4];

    auto qr_tile = [&](int ju) {  // QR tile: QR[row][16*ju + col] = q[row]·relk[c0w+16*ju+col]
      f32x4 acc = {0.f, 0.f, 0.f, 0.f};
      int t = c0w + 16 * ju + c16;
      const bf16x8* b0 = (const bf16x8*)(relk + t * DDIM + grp * 8);
      const bf16x8* b1 = (const bf16x8*)(relk + t * DDIM + 32 + grp * 8);
      acc = mfma16(qa[0], *b0, acc);
      acc = mfma16(qa[1], *b1, acc);
#pragma unroll
      for (int r = 0; r < 4; ++r) ring[w][ju & 1][grp * 4 + r][c16] = acc[r];
    };

    qr_tile(16 * c + 3);
#pragma unroll
    for (int jtl = 0; jtl < 16; ++jtl) {
      const int jt = 16 * c + jtl;
      qr_tile(jt + 4);
      f32x4 acc = {0.f, 0.f, 0.f, 0.f};
      {
        int krow = 16 * jtl + c16;
        const bf16x8* bA = (const bf16x8*)&bufA[krow * 64 + ((grp * 8) ^ swze(krow))];
        const bf16x8* bB = (const bf16x8*)&bufA[krow * 64 + ((32 + grp * 8) ^ swze(krow))];
        acc = mfma16(qa[0], *bA, acc);
        acc = mfma16(qa[1], *bB, acc);
      }
      const int y = 16 * jt + c16;
#pragma unroll
      for (int r = 0; r < 4; ++r) {
        const int row = grp * 4 + r;
        // u = y - row + 63 = 16*(jt+3) + (c16 + 15 - row)
        const int sk = c16 + 15 - row;
        float qrv = ring[w][(jtl + 3 + (sk >> 4)) & 1][row][sk & 15];
        float val = acc[r] + qrv;
        sv[jtl][r] = (y <= row_base + row + 256) ? val : -1e9f;
      }
    }

    // ---- online softmax (exact, 2 chunks) ----
    float al[4];
#pragma unroll
    for (int r = 0; r < 4; ++r) {
      float mc = sv[0][r];
#pragma unroll
      for (int jtl = 1; jtl < 16; ++jtl) mc = fmaxf(mc, sv[jtl][r]);
#pragma unroll
      for (int off = 1; off < 16; off <<= 1) mc = fmaxf(mc, __shfl_xor(mc, off, 64));
      float mn = fmaxf(mrun[r], mc);
      al[r] = __expf(mrun[r] - mn);
      mrun[r] = mn;
    }
#pragma unroll
    for (int r = 0; r < 4; ++r) {
      const int row = grp * 4 + r;
      const int prow = 16 * w + row;
      float ps = 0.f;
#pragma unroll
      for (int jtl = 0; jtl < 16; ++jtl) {
        float pv = __expf(sv[jtl][r] - mrun[r]);
        ps += pv;
        pbuf[prow * 256 + ((16 * jtl + c16) ^ swze(prow))] = (__bf16)pv;
      }
#pragma unroll
      for (int off = 1; off < 16; off <<= 1) ps += __shfl_xor(ps, off, 64);
      lsum[r] = lsum[r] * al[r] + ps;
#pragma unroll
      for (int jd = 0; jd < 4; ++jd) o[jd][r] *= al[r];
    }

    __syncthreads();
    // ---- stage vT chunk (transposed: vT[d][yc]) ----
    {
      const int ty = tid >> 3, td = tid & 7;
      const int d0 = td * 8;
      const float* vb = vg + (size_t)(bh * LSEQ + (nblk + c - 1) * QS) * DDIM;
#pragma unroll
      for (int rep = 0; rep < 8; ++rep) {
        int yc = ty + rep * 32;
        const float4* sp = (const float4*)(vb + yc * DDIM + d0);
        float ff[8] = {sp[0].x, sp[0].y, sp[0].z, sp[0].w, sp[1].x, sp[1].y, sp[1].z, sp[1].w};
#pragma unroll
        for (int i = 0; i < 8; ++i) {
          int d = d0 + i;
          bufA[d * 256 + (yc ^ swze(d))] = (__bf16)ff[i];
        }
      }
    }
    __syncthreads();

    // ---- O += P @ V ----
#pragma unroll
    for (int ks = 0; ks < 8; ++ks) {
      const int prow = 16 * w + c16;
      bf16x8 aP = *(const bf16x8*)&pbuf[prow * 256 + ((ks * 32 + grp * 8) ^ swze(prow))];
#pragma unroll
      for (int jd = 0; jd < 4; ++jd) {
        int drow = 16 * jd + c16;
        bf16x8 bV = *(const bf16x8*)&bufA[drow * 256 + ((ks * 32 + grp * 8) ^ swze(drow))];
        o[jd] = mfma16(aP, bV, o[jd]);
      }
    }

    // ---- O += skew(P) @ rel_v   (WR[row][u] = P[row][y=u+row-63]) ----
#pragma unroll
    for (int s2 = 0; s2 < 9; ++s2) {
      bf16x8 aW;
      const int row = c16;
      const int prow = 16 * w + row;
#pragma unroll
      for (int i = 0; i < 8; ++i) {
        int yl = 32 * s2 + 8 * grp + i + row - 31;  // y - 256c (c cancels)
        __bf16 pv = (__bf16)0.f;
        if (yl >= 0 && yl < 256) pv = pbuf[prow * 256 + (yl ^ swze(prow))];
        aW[i] = pv;
      }
      const int u0 = 32 * (8 * c + 1 + s2) + 8 * grp;
#pragma unroll
      for (int jd = 0; jd < 4; ++jd) {
        int d = 16 * jd + c16;
        const bf16x8* bR = (const bf16x8*)(relvT + d * RELVT_PITCH + j0w + u0);
        o[jd] = mfma16(aW, *bR, o[jd]);
      }
    }
  }

  // ---- epilogue: normalize and store fp32 ----
  float* ob = outg + (size_t)(bh * LSEQ + nblk * QS + row_base) * DDIM;
#pragma unroll
  for (int r = 0; r < 4; ++r) {
    float inv = 1.0f / lsum[r];
    const int row = grp * 4 + r;
#pragma unroll
    for (int jd = 0; jd < 4; ++jd) {
      ob[row * DDIM + 16 * jd + c16] = o[jd][r] * inv;
    }
  }
}

extern "C" void kernel_launch(void* const* d_in, const int* in_sizes, int n_in,
                              void* d_out, int out_size, void* d_ws, size_t ws_size,
                              hipStream_t stream) {
  const float* q = (const float*)d_in[0];
  const float* k = (const float*)d_in[1];
  const float* v = (const float*)d_in[2];
  const float* rk = (const float*)d_in[3];
  const float* rv = (const float*)d_in[4];

  __bf16* relk = (__bf16*)d_ws;                 // 65728 bf16
  __bf16* relvT = relk + RELK_ELEMS;            // 49152 bf16 (offset 131456 B, 16B-aligned)

  prep_kernel<<<257, 256, 0, stream>>>(rk, rv, relk, relvT);
  attn_kernel<<<2048, 256, 0, stream>>>(q, k, v, relk, relvT, (float*)d_out);
}

// Round 2
// 452.802 us; speedup vs baseline: 1.4439x; 1.4439x over previous
//
#include <hip/hip_runtime.h>

typedef __bf16 bf16x8 __attribute__((ext_vector_type(8)));
typedef float f32x4 __attribute__((ext_vector_type(4)));

#define LSEQ 8192
#define DDIM 64
#define QS 256
#define CHUNK 128
#define VOCAB 1027
#define RELK_ELEMS (VOCAB * DDIM)       // 65728
#define RELVT_PITCH 768
#define RELVT_ELEMS (DDIM * RELVT_PITCH) // 49152

__device__ __forceinline__ int swze(int row) { return ((row ^ (row >> 3)) & 7) << 3; }

__device__ __forceinline__ f32x4 mfma16(bf16x8 a, bf16x8 b, f32x4 c) {
  return __builtin_amdgcn_mfma_f32_16x16x32_bf16(a, b, c, 0, 0, 0);
}

__device__ __forceinline__ bf16x8 cvt8(float4 a, float4 b, float sc) {
  bf16x8 r;
  r[0] = (__bf16)(a.x * sc); r[1] = (__bf16)(a.y * sc);
  r[2] = (__bf16)(a.z * sc); r[3] = (__bf16)(a.w * sc);
  r[4] = (__bf16)(b.x * sc); r[5] = (__bf16)(b.y * sc);
  r[6] = (__bf16)(b.z * sc); r[7] = (__bf16)(b.w * sc);
  return r;
}

// Pre-convert rel tables to bf16: relk[t][d] row-major; relvT[d][j] = rel_v[j+2][d]
__global__ void prep_kernel(const float* __restrict__ rk, const float* __restrict__ rv,
                            __bf16* __restrict__ relk, __bf16* __restrict__ relvT) {
  int i = blockIdx.x * 256 + threadIdx.x;
  if (i < RELK_ELEMS) relk[i] = (__bf16)rk[i];
  if (i < RELVT_ELEMS) {
    int d = i / RELVT_PITCH, j = i - d * RELVT_PITCH;
    relvT[i] = (__bf16)rv[(j + 2) * DDIM + d];
  }
}

// One WG = 64 q-rows of one 256-row block, 4 waves x 16 rows, window 512 in four 128-chunks.
// LDS = 16(K/vT) + 16(P) + 8(ring) = 40KB -> 4 blocks/CU.
__global__ __launch_bounds__(256, 4) void attn_kernel(
    const float* __restrict__ qg, const float* __restrict__ kg, const float* __restrict__ vg,
    const __bf16* __restrict__ relk, const __bf16* __restrict__ relvT,
    float* __restrict__ outg) {
  __shared__ __align__(16) __bf16 bufA[CHUNK * DDIM];  // 16KB: K chunk [128][64] / vT [64][128]
  __shared__ __align__(16) __bf16 pbuf[64 * CHUNK];    // 16KB: P (bf16), per-wave 16-row slabs
  __shared__ float ring[4][2][16][16];                 // 8KB: per-wave QR tile ring

  // XCD-aware decode: 4 row-group siblings of one (bh,n) land on one XCD
  const int phys = blockIdx.x;
  const int xcd = phys & 7;
  const int mseq = phys >> 3;
  const int rg = mseq & 3;
  const int gl = mseq >> 2;
  const int pair = xcd * 64 + gl;  // [0,512)
  const int bh = pair >> 5;
  const int nblk = pair & 31;
  const int x0 = rg * 64;

  const int tid = threadIdx.x;
  const int w = tid >> 6;
  const int lane = tid & 63;
  const int c16 = lane & 15;
  const int grp = lane >> 4;

  const int row_base = x0 + 16 * w;   // wave's first q row within the 256-block
  const int rb16 = row_base >> 4;
  const int c0w = 194 - row_base;     // relk row offset: t = c0w + u
  const int j0w = 192 - row_base;     // relvT col offset (shifted table): j = j0w + u

  // q A-fragments (A[row=c16][k=32*kk+8*grp+i]), pre-scaled by D^-0.5 = 1/8
  bf16x8 qa[2];
  {
    const float* qrow = qg + (size_t)(bh * LSEQ + nblk * QS + row_base + c16) * DDIM;
#pragma unroll
    for (int kk = 0; kk < 2; ++kk) {
      const float4* sp = (const float4*)(qrow + kk * 32 + grp * 8);
      qa[kk] = cvt8(sp[0], sp[1], 0.125f);
    }
  }

  f32x4 o[4];
#pragma unroll
  for (int jd = 0; jd < 4; ++jd) o[jd] = f32x4{0.f, 0.f, 0.f, 0.f};
  float mrun[4] = {-1e30f, -1e30f, -1e30f, -1e30f};
  float lsum[4] = {0.f, 0.f, 0.f, 0.f};

  const int cstart = (nblk == 0) ? 2 : 0;  // n=0: window cols [0,256) all padding/masked

  for (int c = cstart; c < 4; ++c) {
    __syncthreads();
    // ---- stage K chunk [128][64]: window y = 128c+yc <-> k row (2*nblk-2+c)*128 + yc ----
    {
      const int ty = tid >> 3, td = tid & 7;
      const int d0 = td * 8;
      const float* kb = kg + ((size_t)bh * LSEQ + (size_t)(2 * nblk - 2 + c) * CHUNK) * DDIM;
#pragma unroll
      for (int rep = 0; rep < 4; ++rep) {
        int yc = ty + rep * 32;
        const float4* sp = (const float4*)(kb + yc * DDIM + d0);
        *(bf16x8*)&bufA[yc * 64 + (d0 ^ swze(yc))] = cvt8(sp[0], sp[1], 1.0f);
      }
    }
    __syncthreads();

    // last valid tile for this wave: jt <= rb16+16  ->  jtl < jtl_hi
    int jtl_hi = rb16 + 17 - 8 * c;
    jtl_hi = jtl_hi > 8 ? 8 : jtl_hi;
    const bool active = jtl_hi > 0;

    if (active) {
      // ---- S = q@k^T + skew(q@relk^T), masked ----
      float sv[8][4];

      auto qr_tile = [&](int ju) {  // QR[row][16*ju+col] = q[row]·relk[c0w+16*ju+col]
        f32x4 acc = {0.f, 0.f, 0.f, 0.f};
        int t = c0w + 16 * ju + c16;
        const bf16x8* b0 = (const bf16x8*)(relk + t * DDIM + grp * 8);
        const bf16x8* b1 = (const bf16x8*)(relk + t * DDIM + 32 + grp * 8);
        acc = mfma16(qa[0], *b0, acc);
        acc = mfma16(qa[1], *b1, acc);
#pragma unroll
        for (int r = 0; r < 4; ++r) ring[w][ju & 1][grp * 4 + r][c16] = acc[r];
      };

      qr_tile(8 * c + 3);
#pragma unroll
      for (int jtl = 0; jtl < 8; ++jtl) {
        if (jtl < jtl_hi) {
          const int jt = 8 * c + jtl;
          qr_tile(jt + 4);
          f32x4 acc = {0.f, 0.f, 0.f, 0.f};
          {
            int krow = 16 * jtl + c16;
            const bf16x8* bA = (const bf16x8*)&bufA[krow * 64 + ((grp * 8) ^ swze(krow))];
            const bf16x8* bB = (const bf16x8*)&bufA[krow * 64 + ((32 + grp * 8) ^ swze(krow))];
            acc = mfma16(qa[0], *bA, acc);
            acc = mfma16(qa[1], *bB, acc);
          }
          const int y = 16 * jt + c16;
#pragma unroll
          for (int r = 0; r < 4; ++r) {
            const int row = grp * 4 + r;
            const int sk = c16 + 15 - row;  // u = 16*(jt+3) + sk
            float qrv = ring[w][(jtl + 3 + (sk >> 4)) & 1][row][sk & 15];
            float val = acc[r] + qrv;
            sv[jtl][r] = (y <= row_base + row + 256) ? val : -1e9f;
          }
        }
      }

      // ---- online softmax (exact across chunks) ----
      float al[4];
#pragma unroll
      for (int r = 0; r < 4; ++r) {
        float mc = -1e30f;
#pragma unroll
        for (int jtl = 0; jtl < 8; ++jtl)
          if (jtl < jtl_hi) mc = fmaxf(mc, sv[jtl][r]);
#pragma unroll
        for (int off = 1; off < 16; off <<= 1) mc = fmaxf(mc, __shfl_xor(mc, off, 64));
        float mn = fmaxf(mrun[r], mc);
        al[r] = __expf(mrun[r] - mn);
        mrun[r] = mn;
      }
#pragma unroll
      for (int r = 0; r < 4; ++r) {
        const int row = grp * 4 + r;
        const int prow = 16 * w + row;
        float ps = 0.f;
#pragma unroll
        for (int jtl = 0; jtl < 8; ++jtl) {
          float pv = 0.f;
          if (jtl < jtl_hi) pv = __expf(sv[jtl][r] - mrun[r]);
          ps += pv;
          pbuf[prow * CHUNK + ((16 * jtl + c16) ^ swze(prow))] = (__bf16)pv;  // zero-fills tail
        }
#pragma unroll
        for (int off = 1; off < 16; off <<= 1) ps += __shfl_xor(ps, off, 64);
        lsum[r] = lsum[r] * al[r] + ps;
#pragma unroll
        for (int jd = 0; jd < 4; ++jd) o[jd][r] *= al[r];
      }
    }

    __syncthreads();
    // ---- stage vT chunk [64][128] (transposed) ----
    {
      const int ty = tid >> 3, td = tid & 7;
      const int d0 = td * 8;
      const float* vb = vg + ((size_t)bh * LSEQ + (size_t)(2 * nblk - 2 + c) * CHUNK) * DDIM;
#pragma unroll
      for (int rep = 0; rep < 4; ++rep) {
        int yc = ty + rep * 32;
        const float4* sp = (const float4*)(vb + yc * DDIM + d0);
        float ff[8] = {sp[0].x, sp[0].y, sp[0].z, sp[0].w, sp[1].x, sp[1].y, sp[1].z, sp[1].w};
#pragma unroll
        for (int i = 0; i < 8; ++i) {
          int d = d0 + i;
          bufA[d * CHUNK + (yc ^ swze(d))] = (__bf16)ff[i];
        }
      }
    }
    __syncthreads();

    if (active) {
      // ---- O += P @ V ----
      const int prow = 16 * w + c16;
#pragma unroll
      for (int ks = 0; ks < 4; ++ks) {
        bf16x8 aP = *(const bf16x8*)&pbuf[prow * CHUNK + ((ks * 32 + grp * 8) ^ swze(prow))];
#pragma unroll
        for (int jd = 0; jd < 4; ++jd) {
          int drow = 16 * jd + c16;
          bf16x8 bV = *(const bf16x8*)&bufA[drow * CHUNK + ((ks * 32 + grp * 8) ^ swze(drow))];
          o[jd] = mfma16(aP, bV, o[jd]);
        }
      }

      // ---- O += skew(P) @ rel_v   (u = y - row + 63; u0 = 128c+32+32*s2+8*grp) ----
#pragma unroll
      for (int s2 = 0; s2 < 5; ++s2) {
        bf16x8 aW;
        const int row = c16;
#pragma unroll
        for (int i = 0; i < 8; ++i) {
          int yl = 32 * s2 + 8 * grp + i + row - 31;  // chunk-local y
          __bf16 pv = (__bf16)0.f;
          if (yl >= 0 && yl < CHUNK) pv = pbuf[prow * CHUNK + (yl ^ swze(prow))];
          aW[i] = pv;
        }
        const int u0 = 128 * c + 32 + 32 * s2 + 8 * grp;
#pragma unroll
        for (int jd = 0; jd < 4; ++jd) {
          int d = 16 * jd + c16;
          const bf16x8* bR = (const bf16x8*)(relvT + d * RELVT_PITCH + j0w + u0);
          o[jd] = mfma16(aW, *bR, o[jd]);
        }
      }
    }
  }

  // ---- epilogue: normalize and store fp32 ----
  float* ob = outg + (size_t)(bh * LSEQ + nblk * QS + row_base) * DDIM;
#pragma unroll
  for (int r = 0; r < 4; ++r) {
    float inv = 1.0f / lsum[r];
    const int row = grp * 4 + r;
#pragma unroll
    for (int jd = 0; jd < 4; ++jd) {
      ob[row * DDIM + 16 * jd + c16] = o[jd][r] * inv;
    }
  }
}

extern "C" void kernel_launch(void* const* d_in, const int* in_sizes, int n_in,
                              void* d_out, int out_size, void* d_ws, size_t ws_size,
                              hipStream_t stream) {
  const float* q = (const float*)d_in[0];
  const float* k = (const float*)d_in[1];
  const float* v = (const float*)d_in[2];
  const float* rk = (const float*)d_in[3];
  const float* rv = (const float*)d_in[4];

  __bf16* relk = (__bf16*)d_ws;                 // 65728 bf16
  __bf16* relvT = relk + RELK_ELEMS;            // 49152 bf16

  prep_kernel<<<257, 256, 0, stream>>>(rk, rv, relk, relvT);
  attn_kernel<<<2048, 256, 0, stream>>>(q, k, v, relk, relvT, (float*)d_out);
}

// Round 4
// 288.183 us; speedup vs baseline: 2.2687x; 1.5712x over previous
//
#include <hip/hip_runtime.h>

typedef __bf16 bf16x8 __attribute__((ext_vector_type(8)));
typedef __bf16 bf16x4 __attribute__((ext_vector_type(4)));
typedef float f32x4 __attribute__((ext_vector_type(4)));

#define LSEQ 8192
#define DDIM 64
#define QS 256
#define CHUNK 128
#define VOCAB 1027
#define RELK_ELEMS (VOCAB * DDIM)        // 65728
#define RELVT_PITCH 768
#define RELVT_ELEMS (DDIM * RELVT_PITCH) // 49152

#define WS_RELK_OFF 0
#define WS_RELVT_OFF 131456
#define WS_KBF_OFF 229888
#define WS_VT_OFF (WS_KBF_OFF + 16777216)
#define WS_NEED ((size_t)WS_VT_OFF + 16777216)

__device__ __forceinline__ int swze(int row) { return ((row ^ (row >> 3)) & 7) << 3; }

__device__ __forceinline__ f32x4 mfma16(bf16x8 a, bf16x8 b, f32x4 c) {
  return __builtin_amdgcn_mfma_f32_16x16x32_bf16(a, b, c, 0, 0, 0);
}

__device__ __forceinline__ bf16x8 cvt8(float4 a, float4 b, float sc) {
  bf16x8 r;
  r[0] = (__bf16)(a.x * sc); r[1] = (__bf16)(a.y * sc);
  r[2] = (__bf16)(a.z * sc); r[3] = (__bf16)(a.w * sc);
  r[4] = (__bf16)(b.x * sc); r[5] = (__bf16)(b.y * sc);
  r[6] = (__bf16)(b.z * sc); r[7] = (__bf16)(b.w * sc);
  return r;
}

__global__ void prep_rel(const float* __restrict__ rk, const float* __restrict__ rv,
                         __bf16* __restrict__ relk, __bf16* __restrict__ relvT) {
  int i = blockIdx.x * 256 + threadIdx.x;
  if (i < RELK_ELEMS) relk[i] = (__bf16)rk[i];
  if (i < RELVT_ELEMS) {
    int d = i / RELVT_PITCH, j = i - d * RELVT_PITCH;
    relvT[i] = (__bf16)rv[(j + 2) * DDIM + d];
  }
}

__global__ void prep_kbf(const float* __restrict__ k, __bf16* __restrict__ kb) {
  size_t i = ((size_t)blockIdx.x * 256 + threadIdx.x) * 8;
  float4 a = *(const float4*)(k + i);
  float4 b = *(const float4*)(k + i + 4);
  *(bf16x8*)(kb + i) = cvt8(a, b, 1.0f);
}

__global__ void prep_vT(const float* __restrict__ v, __bf16* __restrict__ vT) {
  __shared__ float tile[64][65];
  const int bh = blockIdx.y;
  const int y0 = blockIdx.x * 64;
  const int tid = threadIdx.x;
#pragma unroll
  for (int rep = 0; rep < 4; ++rep) {
    int idx = rep * 256 + tid;  // [0,1024)
    int y = idx >> 4, c4 = (idx & 15) * 4;
    const float4 f = *(const float4*)(v + ((size_t)bh * LSEQ + y0 + y) * DDIM + c4);
    tile[y][c4 + 0] = f.x; tile[y][c4 + 1] = f.y;
    tile[y][c4 + 2] = f.z; tile[y][c4 + 3] = f.w;
  }
  __syncthreads();
#pragma unroll
  for (int rep = 0; rep < 4; ++rep) {
    int idx = rep * 256 + tid;
    int d = idx >> 4, yq = (idx & 15) * 4;
    bf16x4 o4;
#pragma unroll
    for (int j = 0; j < 4; ++j) o4[j] = (__bf16)tile[yq + j][d];
    *(bf16x4*)(vT + ((size_t)bh * DDIM + d) * LSEQ + y0 + yq) = o4;
  }
}

// One WG = 64 q-rows of one 256-row block, 4 waves x 16 rows, window 512 in four 128-chunks.
// Swapped QK^T: lane(c16,grp) owns q-row c16 -> per-lane row-local softmax.
// ONE online-softmax update per chunk (P in LDS must share the chunk's final max).
template <bool PRECONV>
__global__ __launch_bounds__(256, 3) void attn_kernel(
    const float* __restrict__ qg, const float* __restrict__ kg, const float* __restrict__ vg,
    const __bf16* __restrict__ relk, const __bf16* __restrict__ relvT,
    const __bf16* __restrict__ kbf, const __bf16* __restrict__ vTg,
    float* __restrict__ outg) {
  __shared__ __align__(16) __bf16 bufA[CHUNK * DDIM];  // 16KB: K chunk [128][64] / vT [64][128]
  __shared__ __align__(16) __bf16 pbuf[64 * CHUNK];    // 16KB: P (bf16), per-wave 16-row slabs
  __shared__ float ring[4][2][16][16];                 // 8KB: per-wave QR^T tile ring

  const int phys = blockIdx.x;
  const int xcd = phys & 7;
  const int mseq = phys >> 3;
  const int rg = mseq & 3;
  const int gl = mseq >> 2;
  const int pair = xcd * 64 + gl;  // [0,512)
  const int bh = pair >> 5;
  const int nblk = pair & 31;
  const int x0 = rg * 64;

  const int tid = threadIdx.x;
  const int w = tid >> 6;
  const int lane = tid & 63;
  const int c16 = lane & 15;   // q-row within wave
  const int grp = lane >> 4;

  const int row_base = x0 + 16 * w;
  const int rb16 = row_base >> 4;
  const int c0w = 194 - row_base;  // relk row: t = c0w + u
  const int j0w = 192 - row_base;  // relvT col: j = j0w + u (table shifted by 2)

  // q fragment: Q[q=row_base+c16][d=32*kk+8*grp+i], scaled 1/8 (A- and B-operand compatible)
  bf16x8 qa[2];
  {
    const float* qrow = qg + (size_t)(bh * LSEQ + nblk * QS + row_base + c16) * DDIM;
#pragma unroll
    for (int kk = 0; kk < 2; ++kk) {
      const float4* sp = (const float4*)(qrow + kk * 32 + grp * 8);
      qa[kk] = cvt8(sp[0], sp[1], 0.125f);
    }
  }

  f32x4 o[4];  // o[jd][r] = O[q=4*grp+r][d=16*jd+c16]
#pragma unroll
  for (int jd = 0; jd < 4; ++jd) o[jd] = f32x4{0.f, 0.f, 0.f, 0.f};
  float mrun = -3e38f, lsum = 0.f;  // per-lane: q-row c16

  const int cstart = (nblk == 0) ? 2 : 0;

  for (int c = cstart; c < 4; ++c) {
    __syncthreads();
    // ---- stage K chunk [y(128)][d(64)] swizzled ----
    if constexpr (PRECONV) {
      const __bf16* kb = kbf + ((size_t)bh * LSEQ + (size_t)(2 * nblk - 2 + c) * CHUNK) * DDIM;
#pragma unroll
      for (int rep = 0; rep < 4; ++rep) {
        int b = (w * 4 + rep) * 64 + lane;  // [0,1024) 8-elem blocks
        int y = b >> 3, sc = (b & 7) * 8;
        *(bf16x8*)&bufA[b * 8] = *(const bf16x8*)(kb + y * DDIM + (sc ^ swze(y)));
      }
    } else {
      const int ty = tid >> 3, td = tid & 7;
      const int d0 = td * 8;
      const float* kb = kg + ((size_t)bh * LSEQ + (size_t)(2 * nblk - 2 + c) * CHUNK) * DDIM;
#pragma unroll
      for (int rep = 0; rep < 4; ++rep) {
        int yc = ty + rep * 32;
        const float4* sp = (const float4*)(kb + yc * DDIM + d0);
        *(bf16x8*)&bufA[yc * 64 + (d0 ^ swze(yc))] = cvt8(sp[0], sp[1], 1.0f);
      }
    }
    __syncthreads();

    int jtl_hi = rb16 + 17 - 8 * c;
    jtl_hi = jtl_hi > 8 ? 8 : jtl_hi;
    const bool active = jtl_hi > 0;

    if (active) {
      const int prow = 16 * w + c16;
      // QR^T tile ju: QR[q=c16][u=16*ju+4*grp+r] -> ring[ju&1][u&15][q]
      auto qr_tile = [&](int ju) {
        f32x4 acc = {0.f, 0.f, 0.f, 0.f};
        int t = c0w + 16 * ju + c16;
        const bf16x8* b0 = (const bf16x8*)(relk + t * DDIM + 8 * grp);
        const bf16x8* b1 = (const bf16x8*)(relk + t * DDIM + 32 + 8 * grp);
        acc = mfma16(*b0, qa[0], acc);
        acc = mfma16(*b1, qa[1], acc);
#pragma unroll
        for (int r = 0; r < 4; ++r) ring[w][ju & 1][4 * grp + r][c16] = acc[r];
      };

      float sv[8][4];  // sv[jtl][r] = S[q=c16][y=16*(8c+jtl)+4*grp+r]
      qr_tile(8 * c + 3);
#pragma unroll
      for (int jtl = 0; jtl < 8; ++jtl) {
        if (jtl < jtl_hi) {
          const int jt = 8 * c + jtl;
          qr_tile(jt + 4);
          f32x4 acc = {0.f, 0.f, 0.f, 0.f};
          int krow = 16 * jtl + c16;
          const bf16x8 aK0 = *(const bf16x8*)&bufA[krow * 64 + ((8 * grp) ^ swze(krow))];
          const bf16x8 aK1 = *(const bf16x8*)&bufA[krow * 64 + ((32 + 8 * grp) ^ swze(krow))];
          acc = mfma16(aK0, qa[0], acc);
          acc = mfma16(aK1, qa[1], acc);
#pragma unroll
          for (int r = 0; r < 4; ++r) {
            int sk = 4 * grp + r + 15 - c16;  // u = 16*(jt+3)+sk
            float qrv = ring[w][(jt + 3 + (sk >> 4)) & 1][sk & 15][c16];
            int yv = 16 * jt + 4 * grp + r;
            sv[jtl][r] = (yv <= row_base + c16 + 256) ? (acc[r] + qrv) : -1e9f;
          }
        }
      }

      // ---- single online-softmax update for the whole chunk ----
      float mc = -3e38f;
#pragma unroll
      for (int jtl = 0; jtl < 8; ++jtl)
        if (jtl < jtl_hi) {
#pragma unroll
          for (int r = 0; r < 4; ++r) mc = fmaxf(mc, sv[jtl][r]);
        }
      mc = fmaxf(mc, __shfl_xor(mc, 16));
      mc = fmaxf(mc, __shfl_xor(mc, 32));
      float mn = fmaxf(mrun, mc);
      float al = __expf(mrun - mn);
      mrun = mn;
#pragma unroll
      for (int r = 0; r < 4; ++r) {
        float alr = __shfl(al, 4 * grp + r);
#pragma unroll
        for (int jd = 0; jd < 4; ++jd) o[jd][r] *= alr;
      }
      float ps = 0.f;
#pragma unroll
      for (int jtl = 0; jtl < 8; ++jtl) {
        bf16x4 pw;
#pragma unroll
        for (int r = 0; r < 4; ++r) {
          float pv = 0.f;
          if (jtl < jtl_hi) pv = __expf(sv[jtl][r] - mrun);
          ps += pv;
          pw[r] = (__bf16)pv;
        }
        *(bf16x4*)&pbuf[prow * CHUNK + ((16 * jtl + 4 * grp) ^ swze(prow))] = pw;
      }
      ps += __shfl_xor(ps, 16);
      ps += __shfl_xor(ps, 32);
      lsum = lsum * al + ps;
    }

    __syncthreads();
    // ---- stage vT chunk [d(64)][y(128)] swizzled ----
    if constexpr (PRECONV) {
      const __bf16* vb = vTg + (size_t)bh * DDIM * LSEQ;
      const int y0g = (2 * nblk - 2 + c) * CHUNK;
#pragma unroll
      for (int rep = 0; rep < 4; ++rep) {
        int b = (w * 4 + rep) * 64 + lane;  // [0,1024)
        int d = b >> 4, sc = (b & 15) * 8;
        *(bf16x8*)&bufA[b * 8] = *(const bf16x8*)(vb + (size_t)d * LSEQ + y0g + (sc ^ swze(d)));
      }
    } else {
      const int ty = tid >> 3, td = tid & 7;
      const int d0 = td * 8;
      const float* vb = vg + ((size_t)bh * LSEQ + (size_t)(2 * nblk - 2 + c) * CHUNK) * DDIM;
#pragma unroll
      for (int rep = 0; rep < 4; ++rep) {
        int yc = ty + rep * 32;
        const float4* sp = (const float4*)(vb + yc * DDIM + d0);
        float ff[8] = {sp[0].x, sp[0].y, sp[0].z, sp[0].w, sp[1].x, sp[1].y, sp[1].z, sp[1].w};
#pragma unroll
        for (int i = 0; i < 8; ++i) {
          int d = d0 + i;
          bufA[d * CHUNK + (yc ^ swze(d))] = (__bf16)ff[i];
        }
      }
    }
    __syncthreads();

    if (active) {
      const int prow = 16 * w + c16;
      const int ks_hi = (jtl_hi + 1) >> 1;
#pragma unroll
      for (int ks = 0; ks < 4; ++ks) {
        if (ks < ks_hi) {
          bf16x8 aP = *(const bf16x8*)&pbuf[prow * CHUNK + ((32 * ks + 8 * grp) ^ swze(prow))];
#pragma unroll
          for (int jd = 0; jd < 4; ++jd) {
            int drow = 16 * jd + c16;
            bf16x8 bV = *(const bf16x8*)&bufA[drow * CHUNK + ((32 * ks + 8 * grp) ^ swze(drow))];
            o[jd] = mfma16(aP, bV, o[jd]);
          }
        }
      }
      int s2_hi = (16 * jtl_hi + 62) >> 5;
      s2_hi = s2_hi > 5 ? 5 : s2_hi;
#pragma unroll
      for (int s2 = 0; s2 < 5; ++s2) {
        if (s2 < s2_hi) {
          bf16x8 aW;
#pragma unroll
          for (int i = 0; i < 8; ++i) {
            int yl = 32 * s2 + 8 * grp + i + c16 - 31;
            __bf16 pv = (__bf16)0.f;
            if (yl >= 0 && yl < CHUNK) pv = pbuf[prow * CHUNK + (yl ^ swze(prow))];
            aW[i] = pv;
          }
          const int u0 = 128 * c + 32 + 32 * s2 + 8 * grp;
#pragma unroll
          for (int jd = 0; jd < 4; ++jd) {
            int d = 16 * jd + c16;
            const bf16x8* bR = (const bf16x8*)(relvT + d * RELVT_PITCH + j0w + u0);
            o[jd] = mfma16(aW, *bR, o[jd]);
          }
        }
      }
    }
  }

  // ---- epilogue ----
  float* ob = outg + (size_t)(bh * LSEQ + nblk * QS + row_base) * DDIM;
#pragma unroll
  for (int r = 0; r < 4; ++r) {
    float lr = __shfl(lsum, 4 * grp + r);
    float inv = 1.0f / lr;
#pragma unroll
    for (int jd = 0; jd < 4; ++jd) {
      ob[(4 * grp + r) * DDIM + 16 * jd + c16] = o[jd][r] * inv;
    }
  }
}

extern "C" void kernel_launch(void* const* d_in, const int* in_sizes, int n_in,
                              void* d_out, int out_size, void* d_ws, size_t ws_size,
                              hipStream_t stream) {
  const float* q = (const float*)d_in[0];
  const float* k = (const float*)d_in[1];
  const float* v = (const float*)d_in[2];
  const float* rk = (const float*)d_in[3];
  const float* rv = (const float*)d_in[4];

  char* ws = (char*)d_ws;
  __bf16* relk = (__bf16*)(ws + WS_RELK_OFF);
  __bf16* relvT = (__bf16*)(ws + WS_RELVT_OFF);
  __bf16* kbf = (__bf16*)(ws + WS_KBF_OFF);
  __bf16* vT = (__bf16*)(ws + WS_VT_OFF);

  prep_rel<<<257, 256, 0, stream>>>(rk, rv, relk, relvT);
  if (ws_size >= WS_NEED) {
    prep_kbf<<<4096, 256, 0, stream>>>(k, kbf);
    prep_vT<<<dim3(128, 16), 256, 0, stream>>>(v, vT);
    attn_kernel<true><<<2048, 256, 0, stream>>>(q, k, v, relk, relvT, kbf, vT, (float*)d_out);
  } else {
    attn_kernel<false><<<2048, 256, 0, stream>>>(q, k, v, relk, relvT, relk, relk, (float*)d_out);
  }
}